// Round 1
// baseline (2334.165 us; speedup 1.0000x reference)
//
#include <hip/hip_runtime.h>

#define DD 96   // feature dim
#define DQ 24   // DD/4 (float4 chunks per row)

// ---------------- zero workspace ----------------
__global__ void zero_kernel(float4* p, int n4) {
    int i = blockIdx.x * blockDim.x + threadIdx.x;
    int stride = gridDim.x * blockDim.x;
    for (; i < n4; i += stride) p[i] = make_float4(0.f, 0.f, 0.f, 0.f);
}

// ---------------- V -> E scatter: esum[e] += X[v], cnt[e] += 1 ----------------
__global__ void scat_ve(const float4* __restrict__ X, const int* __restrict__ vtx,
                        const int* __restrict__ edg, float* __restrict__ esum,
                        float* __restrict__ cnt, int M) {
    int t = blockIdx.x * blockDim.x + threadIdx.x;
    int total = M * DQ;
    int stride = gridDim.x * blockDim.x;
    for (; t < total; t += stride) {
        int m = t / DQ;
        int q = t - m * DQ;
        int v = vtx[m];
        int e = edg[m];
        float4 x = X[v * DQ + q];
        float* dst = esum + e * DD + q * 4;
        atomicAdd(dst + 0, x.x);
        atomicAdd(dst + 1, x.y);
        atomicAdd(dst + 2, x.z);
        atomicAdd(dst + 3, x.w);
        if (q == 0) atomicAdd(cnt + e, 1.0f);
    }
}

// ---------------- Xe = esum / max(cnt,1) * degE  (in-place on esum) ----------------
__global__ void make_xe(float* __restrict__ esum, const float* __restrict__ cnt,
                        const float* __restrict__ degE, int E) {
    int t = blockIdx.x * blockDim.x + threadIdx.x;
    int total = E * DQ;
    if (t >= total) return;
    int e = t / DQ;
    float s = degE[e] / fmaxf(cnt[e], 1.0f);
    float4* p = (float4*)esum + t;
    float4 x = *p;
    x.x *= s; x.y *= s; x.z *= s; x.w *= s;
    *p = x;
}

// ---------------- E -> V scatter: Xv[v] += Xe[e] ----------------
__global__ void scat_ev(const float4* __restrict__ Xe, const int* __restrict__ vtx,
                        const int* __restrict__ edg, float* __restrict__ Xv, int M) {
    int t = blockIdx.x * blockDim.x + threadIdx.x;
    int total = M * DQ;
    int stride = gridDim.x * blockDim.x;
    for (; t < total; t += stride) {
        int m = t / DQ;
        int q = t - m * DQ;
        int v = vtx[m];
        int e = edg[m];
        float4 x = Xe[e * DQ + q];
        float* dst = Xv + v * DD + q * 4;
        atomicAdd(dst + 0, x.x);
        atomicAdd(dst + 1, x.y);
        atomicAdd(dst + 2, x.z);
        atomicAdd(dst + 3, x.w);
    }
}

// ---------------- M = beta*W + (1-beta)*I ----------------
__global__ void make_m(const float* __restrict__ W, const float* __restrict__ beta_p,
                       float* __restrict__ Mm) {
    int t = blockIdx.x * blockDim.x + threadIdx.x;
    if (t >= DD * DD) return;
    float beta = *beta_p;
    int c = t / DD;
    int k = t - c * DD;
    float m = beta * W[t];
    if (c == k) m += 1.0f - beta;
    Mm[t] = m;
}

// ---------------- epilogue: degV scale, L2 norm, residual, out = Xi @ M^T ----------------
__global__ __launch_bounds__(256) void final_k(const float* __restrict__ Xv,
                                               const float4* __restrict__ X0,
                                               const float* __restrict__ Mm,
                                               const float* __restrict__ degV,
                                               const float* __restrict__ alpha_p,
                                               float* __restrict__ out, int N) {
    __shared__ float Wl[DD * 97];   // padded stride 97 -> conflict-free column reads
    __shared__ float xi[4][DD];     // one row buffer per wave
    for (int i = threadIdx.x; i < DD * DD; i += 256) {
        int c = i / DD;
        int k = i - c * DD;
        Wl[c * 97 + k] = Mm[i];
    }
    __syncthreads();
    float alpha = *alpha_p;
    float oma = 1.0f - alpha;
    int wid = threadIdx.x >> 6;
    int lane = threadIdx.x & 63;
    int gw = blockIdx.x * 4 + wid;
    int nw = gridDim.x * 4;
    for (int r = gw; r < N; r += nw) {
        float4 v = make_float4(0.f, 0.f, 0.f, 0.f);
        float ss = 0.f;
        if (lane < DQ) {
            v = ((const float4*)Xv)[r * DQ + lane];
            float dv = degV[r];
            v.x *= dv; v.y *= dv; v.z *= dv; v.w *= dv;
            ss = v.x * v.x + v.y * v.y + v.z * v.z + v.w * v.w;
        }
        #pragma unroll
        for (int off = 32; off; off >>= 1) ss += __shfl_xor(ss, off);
        float scale = (ss > 0.f) ? (1.0f / sqrtf(ss)) : 0.f;
        if (lane < DQ) {
            float4 x0 = X0[r * DQ + lane];
            float4 xiv;
            xiv.x = oma * scale * v.x + alpha * x0.x;
            xiv.y = oma * scale * v.y + alpha * x0.y;
            xiv.z = oma * scale * v.z + alpha * x0.z;
            xiv.w = oma * scale * v.w + alpha * x0.w;
            *(float4*)&xi[wid][lane * 4] = xiv;
        }
        __builtin_amdgcn_wave_barrier();  // wave-internal LDS write->read ordering
        #pragma unroll
        for (int c = lane; c < DD; c += 64) {
            const float* wr = &Wl[c * 97];
            float acc = 0.f;
            #pragma unroll
            for (int k = 0; k < DD; ++k) acc += xi[wid][k] * wr[k];
            out[r * DD + c] = acc;
        }
    }
}

extern "C" void kernel_launch(void* const* d_in, const int* in_sizes, int n_in,
                              void* d_out, int out_size, void* d_ws, size_t ws_size,
                              hipStream_t stream) {
    const float* X     = (const float*)d_in[0];
    const float* X0    = (const float*)d_in[1];
    const float* W     = (const float*)d_in[2];
    const float* degE  = (const float*)d_in[3];
    const float* degV  = (const float*)d_in[4];
    const int*   vertex = (const int*)d_in[5];
    const int*   edges  = (const int*)d_in[6];
    const float* alpha = (const float*)d_in[7];
    const float* beta  = (const float*)d_in[8];

    int N = in_sizes[0] / DD;   // 50000 nodes
    int E = in_sizes[3];        // 25000 hyperedges
    int M = in_sizes[5];        // 800000 incidence pairs

    float* ws   = (float*)d_ws;
    float* esum = ws;                        // E*DD   (becomes Xe in-place)
    float* cnt  = esum + (size_t)E * DD;     // E
    float* Xv   = cnt + E;                   // N*DD
    float* Mm   = Xv + (size_t)N * DD;       // DD*DD

    int zero_n4 = (E * DD + E + N * DD) / 4; // all divisible by 4 for these sizes
    zero_kernel<<<2048, 256, 0, stream>>>((float4*)ws, zero_n4);

    scat_ve<<<2048, 256, 0, stream>>>((const float4*)X, vertex, edges, esum, cnt, M);

    int xe_threads = E * DQ;
    make_xe<<<(xe_threads + 255) / 256, 256, 0, stream>>>(esum, cnt, degE, E);

    scat_ev<<<2048, 256, 0, stream>>>((const float4*)esum, vertex, edges, Xv, M);

    make_m<<<(DD * DD + 255) / 256, 256, 0, stream>>>(W, beta, Mm);

    final_k<<<1024, 256, 0, stream>>>(Xv, (const float4*)X0, Mm, degV, alpha,
                                      (float*)d_out, N);
}

// Round 2
// 457.168 us; speedup vs baseline: 5.1057x; 5.1057x over previous
//
#include <hip/hip_runtime.h>

#define DD 96   // feature dim
#define DQ 24   // DD/4 (float4 chunks per row)

// ---------------- zero int workspace ----------------
__global__ void zero_i(int* p, int n) {
    int i = blockIdx.x * blockDim.x + threadIdx.x;
    int stride = gridDim.x * blockDim.x;
    for (; i < n; i += stride) p[i] = 0;
}

// ---------------- histogram both index arrays ----------------
__global__ void hist_k(const int* __restrict__ vtx, const int* __restrict__ edg,
                       int* __restrict__ cntV, int* __restrict__ cntE, int M) {
    int m = blockIdx.x * blockDim.x + threadIdx.x;
    int stride = gridDim.x * blockDim.x;
    for (; m < M; m += stride) {
        atomicAdd(&cntE[edg[m]], 1);
        atomicAdd(&cntV[vtx[m]], 1);
    }
}

// ---------------- single-block exclusive scan (n <= ~1M) ----------------
__global__ __launch_bounds__(1024) void scan_k(const int* __restrict__ cnt,
                                               int* __restrict__ off, int n) {
    __shared__ int lds[1024];
    int t = threadIdx.x;
    int chunk = (n + 1023) / 1024;
    int lo = t * chunk;
    int hi = min(lo + chunk, n);
    int s = 0;
    for (int i = lo; i < hi; ++i) s += cnt[i];
    lds[t] = s;
    __syncthreads();
    // Hillis-Steele inclusive scan over the 1024 partial sums
    for (int d = 1; d < 1024; d <<= 1) {
        int val = (t >= d) ? lds[t - d] : 0;
        __syncthreads();
        lds[t] += val;
        __syncthreads();
    }
    int running = lds[t] - s;   // exclusive prefix for this chunk
    for (int i = lo; i < hi; ++i) { int c = cnt[i]; off[i] = running; running += c; }
    if (t == 1023) off[n] = lds[1023];
}

// ---------------- scatter pair payloads into both CSR lists ----------------
__global__ void build_k(const int* __restrict__ vtx, const int* __restrict__ edg,
                        const int* __restrict__ offE, const int* __restrict__ offV,
                        int* __restrict__ curE, int* __restrict__ curV,
                        int* __restrict__ vlist, int* __restrict__ elist, int M) {
    int m = blockIdx.x * blockDim.x + threadIdx.x;
    int stride = gridDim.x * blockDim.x;
    for (; m < M; m += stride) {
        int v = vtx[m];
        int e = edg[m];
        int pE = offE[e] + atomicAdd(&curE[e], 1);
        vlist[pE] = v;
        int pV = offV[v] + atomicAdd(&curV[v], 1);
        elist[pV] = e;
    }
}

// ---------------- V -> E gather-reduce: Xe[e] = mean(X[vlist]) * degE[e] ----------------
__global__ __launch_bounds__(256) void gather_ve(const float4* __restrict__ X,
                                                 const int* __restrict__ offE,
                                                 const int* __restrict__ vlist,
                                                 const float* __restrict__ degE,
                                                 float4* __restrict__ Xe, int E) {
    int t = blockIdx.x * blockDim.x + threadIdx.x;
    if (t >= E * DQ) return;
    int e = t / DQ;
    int q = t - e * DQ;
    int start = offE[e];
    int end = offE[e + 1];
    float4 acc = make_float4(0.f, 0.f, 0.f, 0.f);
    for (int i = start; i < end; ++i) {
        int v = vlist[i];
        float4 x = X[v * DQ + q];
        acc.x += x.x; acc.y += x.y; acc.z += x.z; acc.w += x.w;
    }
    float s = degE[e] / fmaxf((float)(end - start), 1.0f);
    acc.x *= s; acc.y *= s; acc.z *= s; acc.w *= s;
    Xe[t] = acc;
}

// ---------------- E -> V gather-reduce: Xv[v] = sum(Xe[elist]) ----------------
__global__ __launch_bounds__(256) void gather_ev(const float4* __restrict__ Xe,
                                                 const int* __restrict__ offV,
                                                 const int* __restrict__ elist,
                                                 float4* __restrict__ Xv, int N) {
    int t = blockIdx.x * blockDim.x + threadIdx.x;
    if (t >= N * DQ) return;
    int v = t / DQ;
    int q = t - v * DQ;
    int start = offV[v];
    int end = offV[v + 1];
    float4 acc = make_float4(0.f, 0.f, 0.f, 0.f);
    for (int i = start; i < end; ++i) {
        int e = elist[i];
        float4 x = Xe[e * DQ + q];
        acc.x += x.x; acc.y += x.y; acc.z += x.z; acc.w += x.w;
    }
    Xv[t] = acc;
}

// ---------------- M = beta*W + (1-beta)*I ----------------
__global__ void make_m(const float* __restrict__ W, const float* __restrict__ beta_p,
                       float* __restrict__ Mm) {
    int t = blockIdx.x * blockDim.x + threadIdx.x;
    if (t >= DD * DD) return;
    float beta = *beta_p;
    int c = t / DD;
    int k = t - c * DD;
    float m = beta * W[t];
    if (c == k) m += 1.0f - beta;
    Mm[t] = m;
}

// ---------------- epilogue: degV scale, L2 norm, residual, out = Xi @ M^T ----------------
// NOTE: Xv aliases out (d_out). Safe: each wave reads its row fully (register
// data dependence) before writing that same row; rows are wave-exclusive.
__global__ __launch_bounds__(256) void final_k(const float* __restrict__ Xv,
                                               const float4* __restrict__ X0,
                                               const float* __restrict__ Mm,
                                               const float* __restrict__ degV,
                                               const float* __restrict__ alpha_p,
                                               float* __restrict__ out, int N) {
    __shared__ float Wl[DD * 97];   // padded stride 97 -> conflict-free column reads
    __shared__ float xi[4][DD];     // one row buffer per wave
    for (int i = threadIdx.x; i < DD * DD; i += 256) {
        int c = i / DD;
        int k = i - c * DD;
        Wl[c * 97 + k] = Mm[i];
    }
    __syncthreads();
    float alpha = *alpha_p;
    float oma = 1.0f - alpha;
    int wid = threadIdx.x >> 6;
    int lane = threadIdx.x & 63;
    int gw = blockIdx.x * 4 + wid;
    int nw = gridDim.x * 4;
    for (int r = gw; r < N; r += nw) {
        float4 v = make_float4(0.f, 0.f, 0.f, 0.f);
        float ss = 0.f;
        if (lane < DQ) {
            v = ((const float4*)Xv)[r * DQ + lane];
            float dv = degV[r];
            v.x *= dv; v.y *= dv; v.z *= dv; v.w *= dv;
            ss = v.x * v.x + v.y * v.y + v.z * v.z + v.w * v.w;
        }
        #pragma unroll
        for (int off = 32; off; off >>= 1) ss += __shfl_xor(ss, off);
        float scale = (ss > 0.f) ? (1.0f / sqrtf(ss)) : 0.f;
        if (lane < DQ) {
            float4 x0 = X0[r * DQ + lane];
            float4 xiv;
            xiv.x = oma * scale * v.x + alpha * x0.x;
            xiv.y = oma * scale * v.y + alpha * x0.y;
            xiv.z = oma * scale * v.z + alpha * x0.z;
            xiv.w = oma * scale * v.w + alpha * x0.w;
            *(float4*)&xi[wid][lane * 4] = xiv;
        }
        __builtin_amdgcn_wave_barrier();  // wave-internal LDS write->read ordering
        #pragma unroll
        for (int c = lane; c < DD; c += 64) {
            const float* wr = &Wl[c * 97];
            float acc = 0.f;
            #pragma unroll
            for (int k = 0; k < DD; ++k) acc += xi[wid][k] * wr[k];
            out[r * DD + c] = acc;
        }
    }
}

extern "C" void kernel_launch(void* const* d_in, const int* in_sizes, int n_in,
                              void* d_out, int out_size, void* d_ws, size_t ws_size,
                              hipStream_t stream) {
    const float* X      = (const float*)d_in[0];
    const float* X0     = (const float*)d_in[1];
    const float* W      = (const float*)d_in[2];
    const float* degE   = (const float*)d_in[3];
    const float* degV   = (const float*)d_in[4];
    const int*   vertex = (const int*)d_in[5];
    const int*   edges  = (const int*)d_in[6];
    const float* alpha  = (const float*)d_in[7];
    const float* beta   = (const float*)d_in[8];

    int N = in_sizes[0] / DD;   // 50000 nodes
    int E = in_sizes[3];        // 25000 hyperedges
    int M = in_sizes[5];        // 800000 incidence pairs

    // ---- workspace layout: floats first (16B-aligned), then ints ----
    float* Xe = (float*)d_ws;                       // E*DD floats
    float* Mm = Xe + (size_t)E * DD;                // DD*DD floats
    int*   ip = (int*)(Mm + DD * DD);
    int* cntE  = ip;               // E
    int* cntV  = cntE + E;         // N
    int* curE  = cntV + N;         // E
    int* curV  = curE + E;         // N
    int* offE  = curV + N;         // E+1
    int* offV  = offE + E + 1;     // N+1
    int* vlist = offV + N + 1;     // M (vertex ids grouped by edge)
    int* elist = vlist + M;        // M (edge ids grouped by vertex)

    // zero counters + cursors (contiguous 2E+2N ints)
    zero_i<<<160, 256, 0, stream>>>(cntE, 2 * E + 2 * N);

    hist_k<<<1024, 256, 0, stream>>>(vertex, edges, cntV, cntE, M);

    scan_k<<<1, 1024, 0, stream>>>(cntE, offE, E);
    scan_k<<<1, 1024, 0, stream>>>(cntV, offV, N);

    build_k<<<1024, 256, 0, stream>>>(vertex, edges, offE, offV, curE, curV,
                                      vlist, elist, M);

    make_m<<<(DD * DD + 255) / 256, 256, 0, stream>>>(W, beta, Mm);

    gather_ve<<<(E * DQ + 255) / 256, 256, 0, stream>>>((const float4*)X, offE, vlist,
                                                        degE, (float4*)Xe, E);

    // Xv lives directly in d_out (final_k reads row-before-write safely)
    gather_ev<<<(N * DQ + 255) / 256, 256, 0, stream>>>((const float4*)Xe, offV, elist,
                                                        (float4*)d_out, N);

    final_k<<<1024, 256, 0, stream>>>((const float*)d_out, (const float4*)X0, Mm,
                                      degV, alpha, (float*)d_out, N);
}

// Round 3
// 340.943 us; speedup vs baseline: 6.8462x; 1.3409x over previous
//
#include <hip/hip_runtime.h>

#define DD 96   // feature dim
#define DQ 24   // DD/4 (float4 chunks per row)

// ---------------- zero int workspace ----------------
__global__ void zero_i(int* p, int n) {
    int i = blockIdx.x * blockDim.x + threadIdx.x;
    if (i < n) p[i] = 0;
}

// ---------------- histogram both index arrays + record per-pair ranks ----------------
__global__ void hist_k(const int* __restrict__ vtx, const int* __restrict__ edg,
                       int* __restrict__ cntV, int* __restrict__ cntE,
                       ushort2* __restrict__ rank, int M) {
    int m = blockIdx.x * blockDim.x + threadIdx.x;
    if (m >= M) return;
    int v = vtx[m];
    int e = edg[m];
    int rE = atomicAdd(&cntE[e], 1);
    int rV = atomicAdd(&cntV[v], 1);
    ushort2 r;
    r.x = (unsigned short)rE;
    r.y = (unsigned short)rV;
    rank[m] = r;
}

// ---------------- dual single-block exclusive scan (block 0: E, block 1: V) ----------------
__global__ __launch_bounds__(1024) void scan2_k(const int* __restrict__ cntE,
                                                int* __restrict__ offE, int nE,
                                                const int* __restrict__ cntV,
                                                int* __restrict__ offV, int nV) {
    const int* cnt = blockIdx.x ? cntV : cntE;
    int* off = blockIdx.x ? offV : offE;
    int n = blockIdx.x ? nV : nE;
    __shared__ int lds[1024];
    int t = threadIdx.x;
    int chunk = (n + 1023) / 1024;
    int lo = t * chunk;
    int hi = min(lo + chunk, n);
    int s = 0;
    for (int i = lo; i < hi; ++i) s += cnt[i];
    lds[t] = s;
    __syncthreads();
    for (int d = 1; d < 1024; d <<= 1) {
        int val = (t >= d) ? lds[t - d] : 0;
        __syncthreads();
        lds[t] += val;
        __syncthreads();
    }
    int running = lds[t] - s;   // exclusive prefix for this chunk
    for (int i = lo; i < hi; ++i) { int c = cnt[i]; off[i] = running; running += c; }
    if (t == 1023) off[n] = lds[1023];
}

// ---------------- scatter pair payloads into both CSR lists (no atomics) ----------------
__global__ void build_k(const int* __restrict__ vtx, const int* __restrict__ edg,
                        const ushort2* __restrict__ rank,
                        const int* __restrict__ offE, const int* __restrict__ offV,
                        int* __restrict__ vlist, int* __restrict__ elist, int M) {
    int m = blockIdx.x * blockDim.x + threadIdx.x;
    if (m >= M) return;
    int v = vtx[m];
    int e = edg[m];
    ushort2 r = rank[m];
    vlist[offE[e] + r.x] = v;
    elist[offV[v] + r.y] = e;
}

// ---------------- V -> E gather-reduce: Xe[e] = mean(X[vlist]) * degE[e] ----------------
__global__ __launch_bounds__(256) void gather_ve(const float4* __restrict__ X,
                                                 const int* __restrict__ offE,
                                                 const int* __restrict__ vlist,
                                                 const float* __restrict__ degE,
                                                 float4* __restrict__ Xe, int E) {
    int t = blockIdx.x * blockDim.x + threadIdx.x;
    if (t >= E * DQ) return;
    int e = t / DQ;
    int q = t - e * DQ;
    int start = offE[e];
    int end = offE[e + 1];
    float4 acc = make_float4(0.f, 0.f, 0.f, 0.f);
    for (int i = start; i < end; ++i) {
        int v = vlist[i];
        float4 x = X[v * DQ + q];
        acc.x += x.x; acc.y += x.y; acc.z += x.z; acc.w += x.w;
    }
    float s = degE[e] / fmaxf((float)(end - start), 1.0f);
    acc.x *= s; acc.y *= s; acc.z *= s; acc.w *= s;
    Xe[t] = acc;
}

// ---------------- fused E->V gather + degV + L2 norm + residual + (Xi @ M^T) ----------------
__global__ __launch_bounds__(256) void final_k(const float4* __restrict__ Xe,
                                               const int* __restrict__ offV,
                                               const int* __restrict__ elist,
                                               const float4* __restrict__ X0,
                                               const float* __restrict__ W,
                                               const float* __restrict__ degV,
                                               const float* __restrict__ alpha_p,
                                               const float* __restrict__ beta_p,
                                               float* __restrict__ out, int N) {
    __shared__ float Wl[DD * 97];   // M = beta*W + (1-beta)*I, padded stride 97
    __shared__ float xi[4][DD];     // one row buffer per wave
    float beta = *beta_p;
    for (int i = threadIdx.x; i < DD * DD; i += 256) {
        int c = i / DD;
        int k = i - c * DD;
        float m = beta * W[i];
        if (c == k) m += 1.0f - beta;
        Wl[c * 97 + k] = m;
    }
    __syncthreads();
    float alpha = *alpha_p;
    float oma = 1.0f - alpha;
    int wid = threadIdx.x >> 6;
    int lane = threadIdx.x & 63;
    int gw = blockIdx.x * 4 + wid;
    int nw = gridDim.x * 4;
    for (int r = gw; r < N; r += nw) {
        int start = offV[r];
        int end = offV[r + 1];
        // gather on 48 lanes: lane = half*24 + q, each half strides the segment by 2
        float4 acc = make_float4(0.f, 0.f, 0.f, 0.f);
        if (lane < 48) {
            int half = (lane >= DQ) ? 1 : 0;
            int q = lane - half * DQ;
            for (int i = start + half; i < end; i += 2) {
                int e = elist[i];
                float4 x = Xe[e * DQ + q];
                acc.x += x.x; acc.y += x.y; acc.z += x.z; acc.w += x.w;
            }
        }
        // combine the two halves: lane<24 pulls from lane+24 (uniform shfl execution)
        int src = (lane < DQ) ? (lane + DQ) : lane;
        float ox = __shfl(acc.x, src);
        float oy = __shfl(acc.y, src);
        float oz = __shfl(acc.z, src);
        float ow = __shfl(acc.w, src);
        float ss = 0.f;
        if (lane < DQ) {
            acc.x += ox; acc.y += oy; acc.z += oz; acc.w += ow;
            float dv = degV[r];
            acc.x *= dv; acc.y *= dv; acc.z *= dv; acc.w *= dv;
            ss = acc.x * acc.x + acc.y * acc.y + acc.z * acc.z + acc.w * acc.w;
        }
        #pragma unroll
        for (int off = 32; off; off >>= 1) ss += __shfl_xor(ss, off);
        float scale = (ss > 0.f) ? (1.0f / sqrtf(ss)) : 0.f;
        if (lane < DQ) {
            float4 x0 = X0[r * DQ + lane];
            float4 xiv;
            xiv.x = oma * scale * acc.x + alpha * x0.x;
            xiv.y = oma * scale * acc.y + alpha * x0.y;
            xiv.z = oma * scale * acc.z + alpha * x0.z;
            xiv.w = oma * scale * acc.w + alpha * x0.w;
            *(float4*)&xi[wid][lane * 4] = xiv;
        }
        __builtin_amdgcn_wave_barrier();  // wave-internal LDS write->read ordering
        const float4* xv = (const float4*)xi[wid];
        #pragma unroll
        for (int c = lane; c < DD; c += 64) {
            const float* wr = &Wl[c * 97];
            float a0 = 0.f;
            #pragma unroll
            for (int k4 = 0; k4 < DQ; ++k4) {
                float4 xk = xv[k4];            // LDS broadcast (same addr all lanes)
                a0 += xk.x * wr[4 * k4 + 0] + xk.y * wr[4 * k4 + 1]
                    + xk.z * wr[4 * k4 + 2] + xk.w * wr[4 * k4 + 3];
            }
            out[r * DD + c] = a0;
        }
    }
}

extern "C" void kernel_launch(void* const* d_in, const int* in_sizes, int n_in,
                              void* d_out, int out_size, void* d_ws, size_t ws_size,
                              hipStream_t stream) {
    const float* X      = (const float*)d_in[0];
    const float* X0     = (const float*)d_in[1];
    const float* W      = (const float*)d_in[2];
    const float* degE   = (const float*)d_in[3];
    const float* degV   = (const float*)d_in[4];
    const int*   vertex = (const int*)d_in[5];
    const int*   edges  = (const int*)d_in[6];
    const float* alpha  = (const float*)d_in[7];
    const float* beta   = (const float*)d_in[8];

    int N = in_sizes[0] / DD;   // 50000 nodes
    int E = in_sizes[3];        // 25000 hyperedges
    int M = in_sizes[5];        // 800000 incidence pairs

    // ---- workspace layout: floats first (16B-aligned), then ints ----
    float* Xe = (float*)d_ws;                       // E*DD floats
    int*   ip = (int*)(Xe + (size_t)E * DD);
    int* cntE  = ip;               // E   } contiguous for one zero pass
    int* cntV  = cntE + E;         // N   }
    int* offE  = cntV + N;         // E+1
    int* offV  = offE + E + 1;     // N+1
    ushort2* rank = (ushort2*)(offV + N + 1);  // M x 4B
    int* vlist = (int*)(rank + M); // M (vertex ids grouped by edge)
    int* elist = vlist + M;        // M (edge ids grouped by vertex)

    zero_i<<<(E + N + 255) / 256, 256, 0, stream>>>(cntE, E + N);

    hist_k<<<(M + 255) / 256, 256, 0, stream>>>(vertex, edges, cntV, cntE, rank, M);

    scan2_k<<<2, 1024, 0, stream>>>(cntE, offE, E, cntV, offV, N);

    build_k<<<(M + 255) / 256, 256, 0, stream>>>(vertex, edges, rank, offE, offV,
                                                 vlist, elist, M);

    gather_ve<<<(E * DQ + 255) / 256, 256, 0, stream>>>((const float4*)X, offE, vlist,
                                                        degE, (float4*)Xe, E);

    final_k<<<1024, 256, 0, stream>>>((const float4*)Xe, offV, elist,
                                      (const float4*)X0, W, degV, alpha, beta,
                                      (float*)d_out, N);
}

// Round 4
// 255.116 us; speedup vs baseline: 9.1494x; 1.3364x over previous
//
#include <hip/hip_runtime.h>

#define DD 96    // feature dim
#define DQ 24    // DD/4  (float4 chunks)
#define DC 12    // DD/8  (16B bf16 chunks)

typedef __attribute__((ext_vector_type(8))) unsigned short u16x8;
typedef __attribute__((ext_vector_type(8))) short s16x8;
typedef __attribute__((ext_vector_type(4))) float f32x4;

__device__ __forceinline__ unsigned short f2bf(float f) {
    unsigned int u = __builtin_bit_cast(unsigned int, f);
    u += 0x7FFFu + ((u >> 16) & 1u);          // round-to-nearest-even
    return (unsigned short)(u >> 16);
}
__device__ __forceinline__ float bf2f(unsigned short h) {
    unsigned int u = ((unsigned int)h) << 16;
    return __builtin_bit_cast(float, u);
}

// ---------------- zero int workspace ----------------
__global__ void zero_i(int* p, int n) {
    int i = blockIdx.x * blockDim.x + threadIdx.x;
    if (i < n) p[i] = 0;
}

// ---------------- histogram both index arrays + record per-pair ranks ----------------
__global__ void hist_k(const int* __restrict__ vtx, const int* __restrict__ edg,
                       int* __restrict__ cntV, int* __restrict__ cntE,
                       ushort2* __restrict__ rank, int M) {
    int m = blockIdx.x * blockDim.x + threadIdx.x;
    if (m >= M) return;
    int v = vtx[m];
    int e = edg[m];
    int rE = atomicAdd(&cntE[e], 1);
    int rV = atomicAdd(&cntV[v], 1);
    ushort2 r;
    r.x = (unsigned short)rE;
    r.y = (unsigned short)rV;
    rank[m] = r;
}

// ---------------- dual single-block exclusive scan ----------------
__global__ __launch_bounds__(1024) void scan2_k(const int* __restrict__ cntE,
                                                int* __restrict__ offE, int nE,
                                                const int* __restrict__ cntV,
                                                int* __restrict__ offV, int nV) {
    const int* cnt = blockIdx.x ? cntV : cntE;
    int* off = blockIdx.x ? offV : offE;
    int n = blockIdx.x ? nV : nE;
    __shared__ int lds[1024];
    int t = threadIdx.x;
    int chunk = (n + 1023) / 1024;
    int lo = t * chunk;
    int hi = min(lo + chunk, n);
    int s = 0;
    for (int i = lo; i < hi; ++i) s += cnt[i];
    lds[t] = s;
    __syncthreads();
    for (int d = 1; d < 1024; d <<= 1) {
        int val = (t >= d) ? lds[t - d] : 0;
        __syncthreads();
        lds[t] += val;
        __syncthreads();
    }
    int running = lds[t] - s;
    for (int i = lo; i < hi; ++i) { int c = cnt[i]; off[i] = running; running += c; }
    if (t == 1023) off[n] = lds[1023];
}

// ---------------- scatter pair payloads into both CSR lists (no atomics) ----------------
__global__ void build_k(const int* __restrict__ vtx, const int* __restrict__ edg,
                        const ushort2* __restrict__ rank,
                        const int* __restrict__ offE, const int* __restrict__ offV,
                        int* __restrict__ vlist, int* __restrict__ elist, int M) {
    int m = blockIdx.x * blockDim.x + threadIdx.x;
    if (m >= M) return;
    int v = vtx[m];
    int e = edg[m];
    ushort2 r = rank[m];
    vlist[offE[e] + r.x] = v;
    elist[offV[v] + r.y] = e;
}

// ---------------- X fp32 -> bf16 copy ----------------
__global__ void convX_k(const float4* __restrict__ X, u16x8* __restrict__ Xb, int n8) {
    int t = blockIdx.x * blockDim.x + threadIdx.x;
    if (t >= n8) return;
    float4 a = X[t * 2];
    float4 b = X[t * 2 + 1];
    u16x8 o;
    o[0] = f2bf(a.x); o[1] = f2bf(a.y); o[2] = f2bf(a.z); o[3] = f2bf(a.w);
    o[4] = f2bf(b.x); o[5] = f2bf(b.y); o[6] = f2bf(b.z); o[7] = f2bf(b.w);
    Xb[t] = o;
}

// ---------------- V->E: wave per edge, Xe[e] = mean(Xb[vlist]) * degE (bf16 out) ------
__global__ __launch_bounds__(256) void gather_ve_w(const u16x8* __restrict__ Xb,
                                                   const int* __restrict__ offE,
                                                   const int* __restrict__ vlist,
                                                   const float* __restrict__ degE,
                                                   u16x8* __restrict__ Xe, int E) {
    int wid = threadIdx.x >> 6;
    int lane = threadIdx.x & 63;
    int e = blockIdx.x * 4 + wid;
    if (e >= E) return;
    int start = offE[e];
    int end = offE[e + 1];
    int part = lane / DC;            // 0..3 (lanes 0-47), garbage 48-63 (unused)
    int chunk = lane - part * DC;
    float acc[8] = {0.f, 0.f, 0.f, 0.f, 0.f, 0.f, 0.f, 0.f};
    if (lane < 48) {
        for (int i = start + part; i < end; i += 4) {
            int v = vlist[i];
            u16x8 x = Xb[v * DC + chunk];
            #pragma unroll
            for (int j = 0; j < 8; ++j) acc[j] += bf2f(x[j]);
        }
    }
    #pragma unroll
    for (int j = 0; j < 8; ++j) {
        float o = __shfl(acc[j], (lane + 24) & 63);
        if (lane < 24) acc[j] += o;
    }
    #pragma unroll
    for (int j = 0; j < 8; ++j) {
        float o = __shfl(acc[j], (lane + 12) & 63);
        if (lane < 12) acc[j] += o;
    }
    if (lane < DC) {
        float s = degE[e] / fmaxf((float)(end - start), 1.0f);
        u16x8 o;
        #pragma unroll
        for (int j = 0; j < 8; ++j) o[j] = f2bf(acc[j] * s);
        Xe[e * DC + chunk] = o;
    }
}

// ---- E->V: wave per node, Xv=sum(Xe[elist]); degV, L2-norm, residual -> Xi bf16 ----
__global__ __launch_bounds__(256) void gather_norm_w(const u16x8* __restrict__ Xe,
                                                     const int* __restrict__ offV,
                                                     const int* __restrict__ elist,
                                                     const float4* __restrict__ X0,
                                                     const float* __restrict__ degV,
                                                     const float* __restrict__ alpha_p,
                                                     u16x8* __restrict__ Xi, int N) {
    int wid = threadIdx.x >> 6;
    int lane = threadIdx.x & 63;
    int r = blockIdx.x * 4 + wid;
    if (r >= N) return;
    int start = offV[r];
    int end = offV[r + 1];
    int part = lane / DC;
    int chunk = lane - part * DC;
    float acc[8] = {0.f, 0.f, 0.f, 0.f, 0.f, 0.f, 0.f, 0.f};
    if (lane < 48) {
        for (int i = start + part; i < end; i += 4) {
            int e = elist[i];
            u16x8 x = Xe[e * DC + chunk];
            #pragma unroll
            for (int j = 0; j < 8; ++j) acc[j] += bf2f(x[j]);
        }
    }
    #pragma unroll
    for (int j = 0; j < 8; ++j) {
        float o = __shfl(acc[j], (lane + 24) & 63);
        if (lane < 24) acc[j] += o;
    }
    #pragma unroll
    for (int j = 0; j < 8; ++j) {
        float o = __shfl(acc[j], (lane + 12) & 63);
        if (lane < 12) acc[j] += o;
    }
    float ss = 0.f;
    if (lane < DC) {
        float dv = degV[r];
        #pragma unroll
        for (int j = 0; j < 8; ++j) { acc[j] *= dv; ss += acc[j] * acc[j]; }
    }
    #pragma unroll
    for (int off = 32; off; off >>= 1) ss += __shfl_xor(ss, off);
    float scale = (ss > 0.f) ? (1.0f / sqrtf(ss)) : 0.f;
    if (lane < DC) {
        float alpha = *alpha_p;
        float oma = 1.0f - alpha;
        float4 a = X0[r * DQ + chunk * 2];
        float4 b = X0[r * DQ + chunk * 2 + 1];
        float x0v[8] = {a.x, a.y, a.z, a.w, b.x, b.y, b.z, b.w};
        u16x8 o;
        #pragma unroll
        for (int j = 0; j < 8; ++j) o[j] = f2bf(oma * scale * acc[j] + alpha * x0v[j]);
        Xi[r * DC + chunk] = o;
    }
}

// ---------------- out = Xi @ M^T via MFMA bf16, M = beta*W + (1-beta)*I --------------
__global__ __launch_bounds__(256) void gemm_k(const u16x8* __restrict__ Xi,
                                              const float* __restrict__ W,
                                              const float* __restrict__ beta_p,
                                              float* __restrict__ out, int N) {
    __shared__ unsigned short Ml[DD][104];   // row pitch 104 bf16 = 13 x 16B slots (odd -> conflict-free)
    float beta = *beta_p;
    for (int i = threadIdx.x; i < DD * DD; i += 256) {
        int c = i / DD;
        int k = i - c * DD;
        float m = beta * W[i];
        if (c == k) m += 1.0f - beta;
        Ml[c][k] = f2bf(m);
    }
    __syncthreads();
    int wid = threadIdx.x >> 6;
    int lane = threadIdx.x & 63;
    int lrow = lane & 15;            // A row / B col / C col selector
    int lk = (lane >> 4) * 8;        // k-offset within 32-wide K step
    // 18 B-frags in registers: Bf[ct][ks] <- M[ct*16+lrow][ks*32+lk .. +7]
    s16x8 Bf[6][3];
    #pragma unroll
    for (int ct = 0; ct < 6; ++ct)
        #pragma unroll
        for (int ks = 0; ks < 3; ++ks)
            Bf[ct][ks] = *(const s16x8*)&Ml[ct * 16 + lrow][ks * 32 + lk];
    int ntile = (N + 15) / 16;
    int tile = blockIdx.x * 4 + wid;
    if (tile >= ntile) return;
    int r0 = tile * 16;
    const s16x8* xr = (const s16x8*)Xi + (size_t)(r0 + lrow) * DC + (lane >> 4);
    f32x4 acc[6] = {};
    #pragma unroll
    for (int ks = 0; ks < 3; ++ks) {
        s16x8 a = xr[ks * 4];        // Xi[row][ks*32+lk .. +7]
        #pragma unroll
        for (int ct = 0; ct < 6; ++ct)
            acc[ct] = __builtin_amdgcn_mfma_f32_16x16x32_bf16(a, Bf[ct][ks], acc[ct], 0, 0, 0);
    }
    // C/D layout: col = lane&15, row = (lane>>4)*4 + reg   [m89-verified]
    int orow = r0 + (lane >> 4) * 4;
    #pragma unroll
    for (int ct = 0; ct < 6; ++ct)
        #pragma unroll
        for (int rg = 0; rg < 4; ++rg)
            out[(size_t)(orow + rg) * DD + ct * 16 + lrow] = acc[ct][rg];
}

extern "C" void kernel_launch(void* const* d_in, const int* in_sizes, int n_in,
                              void* d_out, int out_size, void* d_ws, size_t ws_size,
                              hipStream_t stream) {
    const float* X      = (const float*)d_in[0];
    const float* X0     = (const float*)d_in[1];
    const float* W      = (const float*)d_in[2];
    const float* degE   = (const float*)d_in[3];
    const float* degV   = (const float*)d_in[4];
    const int*   vertex = (const int*)d_in[5];
    const int*   edges  = (const int*)d_in[6];
    const float* alpha  = (const float*)d_in[7];
    const float* beta   = (const float*)d_in[8];

    int N = in_sizes[0] / DD;   // 50000
    int E = in_sizes[3];        // 25000
    int M = in_sizes[5];        // 800000

    // ---- workspace layout: 16B-aligned bf16 arrays first, then ints ----
    u16x8* Xb = (u16x8*)d_ws;                       // N*DC  (bf16 X)
    u16x8* Xe = Xb + (size_t)N * DC;                // E*DC  (bf16 edge feats)
    u16x8* Xi = Xe + (size_t)E * DC;                // N*DC  (bf16 blended rows)
    int* ip   = (int*)(Xi + (size_t)N * DC);
    int* cntE  = ip;                // E   } zeroed together
    int* cntV  = cntE + E;          // N   }
    int* offE  = cntV + N;          // E+1
    int* offV  = offE + E + 1;      // N+1
    ushort2* rank = (ushort2*)(offV + N + 1);   // M
    int* vlist = (int*)(rank + M);  // M
    int* elist = vlist + M;         // M

    zero_i<<<(E + N + 255) / 256, 256, 0, stream>>>(cntE, E + N);

    hist_k<<<(M + 255) / 256, 256, 0, stream>>>(vertex, edges, cntV, cntE, rank, M);

    convX_k<<<(N * DC + 255) / 256, 256, 0, stream>>>((const float4*)X, Xb, N * DC);

    scan2_k<<<2, 1024, 0, stream>>>(cntE, offE, E, cntV, offV, N);

    build_k<<<(M + 255) / 256, 256, 0, stream>>>(vertex, edges, rank, offE, offV,
                                                 vlist, elist, M);

    gather_ve_w<<<(E + 3) / 4, 256, 0, stream>>>(Xb, offE, vlist, degE, Xe, E);

    gather_norm_w<<<(N + 3) / 4, 256, 0, stream>>>(Xe, offV, elist,
                                                   (const float4*)X0, degV, alpha, Xi, N);

    int ntile = (N + 15) / 16;
    gemm_k<<<(ntile + 3) / 4, 256, 0, stream>>>(Xi, W, beta, (float*)d_out, N);
}

// Round 5
// 200.300 us; speedup vs baseline: 11.6533x; 1.2737x over previous
//
#include <hip/hip_runtime.h>

#define DD 96    // feature dim
#define DQ 24    // DD/4  (float4 chunks)
#define DC 12    // DD/8  (16B bf16 chunks)

typedef __attribute__((ext_vector_type(8))) unsigned short u16x8;
typedef __attribute__((ext_vector_type(8))) short s16x8;
typedef __attribute__((ext_vector_type(4))) float f32x4;

__device__ __forceinline__ unsigned short f2bf(float f) {
    unsigned int u = __builtin_bit_cast(unsigned int, f);
    u += 0x7FFFu + ((u >> 16) & 1u);          // round-to-nearest-even
    return (unsigned short)(u >> 16);
}
__device__ __forceinline__ float bf2f(unsigned short h) {
    unsigned int u = ((unsigned int)h) << 16;
    return __builtin_bit_cast(float, u);
}

// ---------------- zero int workspace ----------------
__global__ void zero_i(int* p, int n) {
    int i = blockIdx.x * blockDim.x + threadIdx.x;
    if (i < n) p[i] = 0;
}

// ---------------- histogram both index arrays + record per-pair ranks ----------------
__global__ void hist_k(const int* __restrict__ vtx, const int* __restrict__ edg,
                       int* __restrict__ cntV, int* __restrict__ cntE,
                       ushort2* __restrict__ rank, int M) {
    int m = blockIdx.x * blockDim.x + threadIdx.x;
    if (m >= M) return;
    int v = vtx[m];
    int e = edg[m];
    int rE = atomicAdd(&cntE[e], 1);
    int rV = atomicAdd(&cntV[v], 1);
    ushort2 r;
    r.x = (unsigned short)rE;
    r.y = (unsigned short)rV;
    rank[m] = r;
}

// ------- dynamic CSR segment allocation: off = waveScan(cnt) + atomic cursor -------
// Edge section: threads [0, Ea); vertex section: threads [Ea, Ea+N), Ea = 256-aligned
// so every block (and wave) is section-uniform.
__global__ __launch_bounds__(256) void alloc_k(const int* __restrict__ cntE,
                                               int* __restrict__ offE, int E,
                                               const int* __restrict__ cntV,
                                               int* __restrict__ offV, int N,
                                               int* __restrict__ cursors) {
    int t = blockIdx.x * blockDim.x + threadIdx.x;
    int lane = threadIdx.x & 63;
    int Ea = (E + 255) & ~255;
    bool isE = t < Ea;
    int idx = isE ? t : t - Ea;
    int n = isE ? E : N;
    const int* cnt = isE ? cntE : cntV;
    int* off = isE ? offE : offV;
    int* cur = cursors + (isE ? 0 : 1);
    bool act = idx < n;
    int c = act ? cnt[idx] : 0;
    int sc = c;                       // inclusive wave scan
    #pragma unroll
    for (int d = 1; d < 64; d <<= 1) {
        int o = __shfl_up(sc, d);
        if (lane >= d) sc += o;
    }
    int total = __shfl(sc, 63);
    int base = 0;
    if (lane == 63) base = atomicAdd(cur, total);
    base = __shfl(base, 63);
    if (act) off[idx] = base + sc - c;
}

// ---------------- scatter pair payloads into both CSR lists (no atomics) ----------------
__global__ void build_k(const int* __restrict__ vtx, const int* __restrict__ edg,
                        const ushort2* __restrict__ rank,
                        const int* __restrict__ offE, const int* __restrict__ offV,
                        int* __restrict__ vlist, int* __restrict__ elist, int M) {
    int m = blockIdx.x * blockDim.x + threadIdx.x;
    if (m >= M) return;
    int v = vtx[m];
    int e = edg[m];
    ushort2 r = rank[m];
    vlist[offE[e] + r.x] = v;
    elist[offV[v] + r.y] = e;
}

// ---------------- X fp32 -> bf16 copy ----------------
__global__ void convX_k(const float4* __restrict__ X, u16x8* __restrict__ Xb, int n8) {
    int t = blockIdx.x * blockDim.x + threadIdx.x;
    if (t >= n8) return;
    float4 a = X[t * 2];
    float4 b = X[t * 2 + 1];
    u16x8 o;
    o[0] = f2bf(a.x); o[1] = f2bf(a.y); o[2] = f2bf(a.z); o[3] = f2bf(a.w);
    o[4] = f2bf(b.x); o[5] = f2bf(b.y); o[6] = f2bf(b.z); o[7] = f2bf(b.w);
    Xb[t] = o;
}

// ---------------- V->E: wave per edge, Xe[e] = mean(Xb[vlist]) * degE (bf16 out) ------
__global__ __launch_bounds__(256) void gather_ve_w(const u16x8* __restrict__ Xb,
                                                   const int* __restrict__ offE,
                                                   const int* __restrict__ cntE,
                                                   const int* __restrict__ vlist,
                                                   const float* __restrict__ degE,
                                                   u16x8* __restrict__ Xe, int E) {
    int wid = threadIdx.x >> 6;
    int lane = threadIdx.x & 63;
    int e = blockIdx.x * 4 + wid;
    if (e >= E) return;
    int start = offE[e];
    int cnt = cntE[e];
    int end = start + cnt;
    int part = lane / DC;            // 0..3 (lanes 0-47)
    int chunk = lane - part * DC;
    float acc[8] = {0.f, 0.f, 0.f, 0.f, 0.f, 0.f, 0.f, 0.f};
    if (lane < 48) {
        for (int i = start + part; i < end; i += 4) {
            int v = vlist[i];
            u16x8 x = Xb[v * DC + chunk];
            #pragma unroll
            for (int j = 0; j < 8; ++j) acc[j] += bf2f(x[j]);
        }
    }
    #pragma unroll
    for (int j = 0; j < 8; ++j) {
        float o = __shfl(acc[j], (lane + 24) & 63);
        if (lane < 24) acc[j] += o;
    }
    #pragma unroll
    for (int j = 0; j < 8; ++j) {
        float o = __shfl(acc[j], (lane + 12) & 63);
        if (lane < 12) acc[j] += o;
    }
    if (lane < DC) {
        float s = degE[e] / fmaxf((float)cnt, 1.0f);
        u16x8 o;
        #pragma unroll
        for (int j = 0; j < 8; ++j) o[j] = f2bf(acc[j] * s);
        Xe[e * DC + chunk] = o;
    }
}

// ---- E->V: wave per node, Xv=sum(Xe[elist]); degV, L2-norm, residual -> Xi bf16 ----
__global__ __launch_bounds__(256) void gather_norm_w(const u16x8* __restrict__ Xe,
                                                     const int* __restrict__ offV,
                                                     const int* __restrict__ cntV,
                                                     const int* __restrict__ elist,
                                                     const float4* __restrict__ X0,
                                                     const float* __restrict__ degV,
                                                     const float* __restrict__ alpha_p,
                                                     u16x8* __restrict__ Xi, int N) {
    int wid = threadIdx.x >> 6;
    int lane = threadIdx.x & 63;
    int r = blockIdx.x * 4 + wid;
    if (r >= N) return;
    int start = offV[r];
    int end = start + cntV[r];
    int part = lane / DC;
    int chunk = lane - part * DC;
    float acc[8] = {0.f, 0.f, 0.f, 0.f, 0.f, 0.f, 0.f, 0.f};
    if (lane < 48) {
        for (int i = start + part; i < end; i += 4) {
            int e = elist[i];
            u16x8 x = Xe[e * DC + chunk];
            #pragma unroll
            for (int j = 0; j < 8; ++j) acc[j] += bf2f(x[j]);
        }
    }
    #pragma unroll
    for (int j = 0; j < 8; ++j) {
        float o = __shfl(acc[j], (lane + 24) & 63);
        if (lane < 24) acc[j] += o;
    }
    #pragma unroll
    for (int j = 0; j < 8; ++j) {
        float o = __shfl(acc[j], (lane + 12) & 63);
        if (lane < 12) acc[j] += o;
    }
    float ss = 0.f;
    if (lane < DC) {
        float dv = degV[r];
        #pragma unroll
        for (int j = 0; j < 8; ++j) { acc[j] *= dv; ss += acc[j] * acc[j]; }
    }
    #pragma unroll
    for (int off = 32; off; off >>= 1) ss += __shfl_xor(ss, off);
    float scale = (ss > 0.f) ? (1.0f / sqrtf(ss)) : 0.f;
    if (lane < DC) {
        float alpha = *alpha_p;
        float oma = 1.0f - alpha;
        float4 a = X0[r * DQ + chunk * 2];
        float4 b = X0[r * DQ + chunk * 2 + 1];
        float x0v[8] = {a.x, a.y, a.z, a.w, b.x, b.y, b.z, b.w};
        u16x8 o;
        #pragma unroll
        for (int j = 0; j < 8; ++j) o[j] = f2bf(oma * scale * acc[j] + alpha * x0v[j]);
        Xi[r * DC + chunk] = o;
    }
}

// ---------------- out = Xi @ M^T via MFMA bf16, M = beta*W + (1-beta)*I --------------
__global__ __launch_bounds__(256) void gemm_k(const u16x8* __restrict__ Xi,
                                              const float* __restrict__ W,
                                              const float* __restrict__ beta_p,
                                              float* __restrict__ out, int N) {
    __shared__ unsigned short Ml[DD][104];   // row pitch 104 bf16 (13 x 16B, odd -> conflict-free)
    float beta = *beta_p;
    for (int i = threadIdx.x; i < DD * DD; i += 256) {
        int c = i / DD;
        int k = i - c * DD;
        float m = beta * W[i];
        if (c == k) m += 1.0f - beta;
        Ml[c][k] = f2bf(m);
    }
    __syncthreads();
    int wid = threadIdx.x >> 6;
    int lane = threadIdx.x & 63;
    int lrow = lane & 15;
    int lk = (lane >> 4) * 8;
    s16x8 Bf[6][3];
    #pragma unroll
    for (int ct = 0; ct < 6; ++ct)
        #pragma unroll
        for (int ks = 0; ks < 3; ++ks)
            Bf[ct][ks] = *(const s16x8*)&Ml[ct * 16 + lrow][ks * 32 + lk];
    int ntile = (N + 15) / 16;
    int tile = blockIdx.x * 4 + wid;
    if (tile >= ntile) return;
    int r0 = tile * 16;
    const s16x8* xr = (const s16x8*)Xi + (size_t)(r0 + lrow) * DC + (lane >> 4);
    f32x4 acc[6] = {};
    #pragma unroll
    for (int ks = 0; ks < 3; ++ks) {
        s16x8 a = xr[ks * 4];
        #pragma unroll
        for (int ct = 0; ct < 6; ++ct)
            acc[ct] = __builtin_amdgcn_mfma_f32_16x16x32_bf16(a, Bf[ct][ks], acc[ct], 0, 0, 0);
    }
    int orow = r0 + (lane >> 4) * 4;
    #pragma unroll
    for (int ct = 0; ct < 6; ++ct)
        #pragma unroll
        for (int rg = 0; rg < 4; ++rg)
            out[(size_t)(orow + rg) * DD + ct * 16 + lrow] = acc[ct][rg];
}

extern "C" void kernel_launch(void* const* d_in, const int* in_sizes, int n_in,
                              void* d_out, int out_size, void* d_ws, size_t ws_size,
                              hipStream_t stream) {
    const float* X      = (const float*)d_in[0];
    const float* X0     = (const float*)d_in[1];
    const float* W      = (const float*)d_in[2];
    const float* degE   = (const float*)d_in[3];
    const float* degV   = (const float*)d_in[4];
    const int*   vertex = (const int*)d_in[5];
    const int*   edges  = (const int*)d_in[6];
    const float* alpha  = (const float*)d_in[7];
    const float* beta   = (const float*)d_in[8];

    int N = in_sizes[0] / DD;   // 50000
    int E = in_sizes[3];        // 25000
    int M = in_sizes[5];        // 800000

    // ---- workspace layout: 16B-aligned bf16 arrays first, then ints ----
    u16x8* Xb = (u16x8*)d_ws;                       // N*DC
    u16x8* Xe = Xb + (size_t)N * DC;                // E*DC
    u16x8* Xi = Xe + (size_t)E * DC;                // N*DC
    int* ip   = (int*)(Xi + (size_t)N * DC);
    int* cntE    = ip;               // E   } zeroed together (E+N+2)
    int* cntV    = cntE + E;         // N   }
    int* cursors = cntV + N;         // 2   }
    int* offE    = cursors + 2;      // E
    int* offV    = offE + E;         // N
    ushort2* rank = (ushort2*)(offV + N);   // M
    int* vlist = (int*)(rank + M);   // M
    int* elist = vlist + M;          // M

    zero_i<<<(E + N + 2 + 255) / 256, 256, 0, stream>>>(cntE, E + N + 2);

    hist_k<<<(M + 255) / 256, 256, 0, stream>>>(vertex, edges, cntV, cntE, rank, M);

    convX_k<<<(N * DC + 255) / 256, 256, 0, stream>>>((const float4*)X, Xb, N * DC);

    int Ea = (E + 255) & ~255;
    alloc_k<<<(Ea + N + 255) / 256, 256, 0, stream>>>(cntE, offE, E, cntV, offV, N,
                                                      cursors);

    build_k<<<(M + 255) / 256, 256, 0, stream>>>(vertex, edges, rank, offE, offV,
                                                 vlist, elist, M);

    gather_ve_w<<<(E + 3) / 4, 256, 0, stream>>>(Xb, offE, cntE, vlist, degE, Xe, E);

    gather_norm_w<<<(N + 3) / 4, 256, 0, stream>>>(Xe, offV, cntV, elist,
                                                   (const float4*)X0, degV, alpha, Xi, N);

    int ntile = (N + 15) / 16;
    gemm_k<<<(ntile + 3) / 4, 256, 0, stream>>>(Xi, W, beta, (float*)d_out, N);
}